// Round 3
// baseline (16.348 us; speedup 1.0000x reference)
//
#include <hip/hip_runtime.h>

#define TOKEN_DIM 32
#define NQ 16
#define LQ 128
#define ND 128
#define LD 128

__global__ __launch_bounds__(256) void coil_maxsim_kernel(
    const float* __restrict__ doc_reps,   // [ND][LD][TOKEN_DIM]
    const float* __restrict__ qry_reps,   // [NQ][LQ][TOKEN_DIM]
    const float* __restrict__ qry_mask,   // [NQ][LQ]
    const int*   __restrict__ doc_ids,    // [ND][LD]
    const int*   __restrict__ qry_ids,    // [NQ][LQ]
    float*       __restrict__ out)        // [NQ][ND]
{
    __shared__ float s_red[8][2];

    const int bid  = blockIdx.x;
    const int n    = bid & (ND - 1);   // doc index
    const int qh   = bid >> 7;         // which q-octet (0/1)
    const int tid  = threadIdx.x;
    const int i    = tid & (LQ - 1);   // query token
    const int qsub = tid >> 7;         // 0/1: which q-quad within the octet

    // ---- Preload the 4 qids + masks this thread needs (coalesced per wave).
    int   qid[4];
    float msk[4];
    #pragma unroll
    for (int k = 0; k < 4; ++k) {
        const int q = qh * 8 + qsub * 4 + k;
        qid[k] = qry_ids[q * LQ + i];
        msk[k] = qry_mask[q * LQ + i];
    }

    // ---- Compare phase: doc ids are block-uniform -> scalar/broadcast loads.
    // Chunk 32 ids at a time (8 int4), compare against all 4 qids -> 16 mask words.
    unsigned m[4][4];   // [k][w]: bits for j in [32w, 32w+32)
    const int4* dip = (const int4*)(doc_ids + n * LD);
    #pragma unroll
    for (int w = 0; w < 4; ++w) {
        int4 c[8];
        #pragma unroll
        for (int p = 0; p < 8; ++p) c[p] = dip[w * 8 + p];
        #pragma unroll
        for (int k = 0; k < 4; ++k) {
            unsigned mm = 0;
            #pragma unroll
            for (int p = 0; p < 8; ++p) {
                mm |= (unsigned)(c[p].x == qid[k]) << (4 * p + 0);
                mm |= (unsigned)(c[p].y == qid[k]) << (4 * p + 1);
                mm |= (unsigned)(c[p].z == qid[k]) << (4 * p + 2);
                mm |= (unsigned)(c[p].w == qid[k]) << (4 * p + 3);
            }
            m[k][w] = mm;
        }
    }

    const float4* dbase = (const float4*)(doc_reps + (size_t)n * LD * TOKEN_DIM);

    // ---- Per-q: walk matches (rare), doc vectors straight from global (L2-resident).
    #pragma unroll
    for (int k = 0; k < 4; ++k) {
        unsigned long long M0 = (unsigned long long)m[k][0] |
                                ((unsigned long long)m[k][1] << 32);
        unsigned long long M1 = (unsigned long long)m[k][2] |
                                ((unsigned long long)m[k][3] << 32);
        const int nmatch = __popcll(M0) + __popcll(M1);

        float4 qr[8];
        if (nmatch != 0) {  // lazy q-vector load, only on lanes with a match
            const int q = qh * 8 + qsub * 4 + k;
            const float4* qv = (const float4*)(qry_reps +
                               (size_t)(q * LQ + i) * TOKEN_DIM);
            #pragma unroll
            for (int kk = 0; kk < 8; ++kk) qr[kk] = qv[kk];
        }

        float best = -INFINITY;
        #pragma unroll
        for (int h = 0; h < 2; ++h) {
            unsigned long long mm = h ? M1 : M0;
            const int jb = h * 64;
            while (__any(mm != 0)) {
                if (mm) {
                    const int j = jb + __ffsll(mm) - 1;
                    mm &= mm - 1;
                    const float4* dv = dbase + j * (TOKEN_DIM / 4);
                    float acc = 0.f;
                    #pragma unroll
                    for (int kk = 0; kk < 8; ++kk) {
                        float4 d = dv[kk];
                        acc += qr[kk].x * d.x + qr[kk].y * d.y +
                               qr[kk].z * d.z + qr[kk].w * d.w;
                    }
                    best = fmaxf(best, acc);
                }
            }
        }
        // jnp.where semantics: non-matching doc tokens contribute 0.0 to the max.
        if (nmatch < LD) best = fmaxf(best, 0.0f);

        float p = (i >= 1) ? best * msk[k] : 0.0f;
        #pragma unroll
        for (int off = 32; off > 0; off >>= 1)
            p += __shfl_down(p, off);
        if ((tid & 63) == 0) s_red[qsub * 4 + k][(tid >> 6) & 1] = p;
    }

    __syncthreads();
    if (tid < 8)
        out[(qh * 8 + tid) * ND + n] = s_red[tid][0] + s_red[tid][1];
}

extern "C" void kernel_launch(void* const* d_in, const int* in_sizes, int n_in,
                              void* d_out, int out_size, void* d_ws, size_t ws_size,
                              hipStream_t stream) {
    const float* doc_reps = (const float*)d_in[0];
    const float* qry_reps = (const float*)d_in[1];
    const float* qry_mask = (const float*)d_in[2];
    const int*   doc_ids  = (const int*)d_in[3];
    const int*   qry_ids  = (const int*)d_in[4];
    float* out = (float*)d_out;

    coil_maxsim_kernel<<<dim3(ND * (NQ / 8)), dim3(256), 0, stream>>>(
        doc_reps, qry_reps, qry_mask, doc_ids, qry_ids, out);
}

// Round 4
// 13.554 us; speedup vs baseline: 1.2061x; 1.2061x over previous
//
#include <hip/hip_runtime.h>

#define TOKEN_DIM 32
#define NQ 16
#define LQ 128
#define ND 128
#define LD 128

__global__ __launch_bounds__(128) void coil_maxsim_kernel(
    const float* __restrict__ doc_reps,   // [ND][LD][TOKEN_DIM]
    const float* __restrict__ qry_reps,   // [NQ][LQ][TOKEN_DIM]
    const float* __restrict__ qry_mask,   // [NQ][LQ]
    const int*   __restrict__ doc_ids,    // [ND][LD]
    const int*   __restrict__ qry_ids,    // [NQ][LQ]
    float*       __restrict__ out)        // [NQ][ND]
{
    __shared__ int   s_ids[LD];
    __shared__ float s_red[2];

    const int bid = blockIdx.x;
    const int q   = bid >> 7;      // bid / ND
    const int n   = bid & 127;     // bid % ND
    const int tid = threadIdx.x;   // one query token i per thread

    // ---- Issue ALL independent loads up front (overlap latencies).
    const int   qid  = qry_ids[q * LQ + tid];
    const float wmsk = qry_mask[q * LQ + tid];
    s_ids[tid] = doc_ids[n * LD + tid];

    // Unconditional q-vector prefetch: L2-resident, hides latency that the
    // lazy-load variant paid serially right before the match walk.
    float4 qr[8];
    {
        const float4* qv = (const float4*)(qry_reps + (size_t)(q * LQ + tid) * TOKEN_DIM);
        #pragma unroll
        for (int k = 0; k < 8; ++k) qr[k] = qv[k];
    }
    __syncthreads();

    // ---- Compare phase: broadcast LDS reads (conflict-free), 128 independent
    // compares per lane -> fully pipelined mask build.
    unsigned m[4];
    const int4* ids4 = (const int4*)s_ids;
    #pragma unroll
    for (int w = 0; w < 4; ++w) {
        unsigned mm = 0;
        #pragma unroll
        for (int p = 0; p < 8; ++p) {
            int4 a = ids4[w * 8 + p];
            mm |= (unsigned)(a.x == qid) << (4 * p + 0);
            mm |= (unsigned)(a.y == qid) << (4 * p + 1);
            mm |= (unsigned)(a.z == qid) << (4 * p + 2);
            mm |= (unsigned)(a.w == qid) << (4 * p + 3);
        }
        m[w] = mm;
    }

    unsigned long long M0 = (unsigned long long)m[0] | ((unsigned long long)m[1] << 32);
    unsigned long long M1 = (unsigned long long)m[2] | ((unsigned long long)m[3] << 32);
    const int nmatch = __popcll(M0) + __popcll(M1);

    // jnp.where semantics folded into init: non-matching doc tokens contribute
    // 0.0 to the max, so unless ALL 128 match, the max is bounded below by 0.
    float best = (nmatch < LD) ? 0.0f : -INFINITY;

    // ---- Match walk: rare (avg ~0.13/lane); doc vectors straight from L2.
    const float4* dbase = (const float4*)(doc_reps + (size_t)n * LD * TOKEN_DIM);
    #pragma unroll
    for (int h = 0; h < 2; ++h) {
        unsigned long long mm = h ? M1 : M0;
        const int jb = h * 64;
        while (__any(mm != 0)) {
            if (mm) {
                const int j = jb + __ffsll(mm) - 1;
                mm &= mm - 1;
                const float4* dv = dbase + j * (TOKEN_DIM / 4);
                float acc = 0.f;
                #pragma unroll
                for (int k = 0; k < 8; ++k) {
                    float4 d = dv[k];
                    acc += qr[k].x * d.x + qr[k].y * d.y + qr[k].z * d.z + qr[k].w * d.w;
                }
                best = fmaxf(best, acc);
            }
        }
    }

    // ---- Mask, skip [CLS] (i==0), reduce 128 -> 1, store.
    float partial = (tid != 0) ? best * wmsk : 0.0f;
    #pragma unroll
    for (int off = 32; off > 0; off >>= 1)
        partial += __shfl_down(partial, off);
    if ((tid & 63) == 0) s_red[tid >> 6] = partial;
    __syncthreads();
    if (tid == 0) out[q * ND + n] = s_red[0] + s_red[1];
}

extern "C" void kernel_launch(void* const* d_in, const int* in_sizes, int n_in,
                              void* d_out, int out_size, void* d_ws, size_t ws_size,
                              hipStream_t stream) {
    const float* doc_reps = (const float*)d_in[0];
    const float* qry_reps = (const float*)d_in[1];
    const float* qry_mask = (const float*)d_in[2];
    const int*   doc_ids  = (const int*)d_in[3];
    const int*   qry_ids  = (const int*)d_in[4];
    float* out = (float*)d_out;

    coil_maxsim_kernel<<<dim3(NQ * ND), dim3(128), 0, stream>>>(
        doc_reps, qry_reps, qry_mask, doc_ids, qry_ids, out);
}